// Round 2
// baseline (471.938 us; speedup 1.0000x reference)
//
#include <hip/hip_runtime.h>

typedef _Float16 f16;
typedef _Float16 f16x8 __attribute__((ext_vector_type(8)));
typedef float f32x4 __attribute__((ext_vector_type(4)));

// ---- workspace layout (bytes) ----
#define WS_ZCNN 0                              // 8192*128 f32 = 4 MiB
#define WS_EWIH (8192*128*4)                   // enc Wih f16 [384][32] (k>=29 zero)
#define WS_EWHH (WS_EWIH + 384*32*2)           // enc Whh f16 [384][128]
#define WS_DWC  (WS_EWHH + 384*128*2)          // dec combined f16 [512][128]
#define WS_DWHH (WS_DWC + 512*128*2)           // dec Whh f16 [384][128]
#define WS_BIAS (WS_DWHH + 384*128*2)          // f32[1024]: e_brz256,e_bxn128,e_bhn128,d_brz256,d_bxn128,d_bhn128

static __device__ __forceinline__ f32x4 mfma16(f16x8 a, f16x8 b, f32x4 c) {
    return __builtin_amdgcn_mfma_f32_16x16x32_f16(a, b, c, 0, 0, 0);
}
static __device__ __forceinline__ float fsig(float x) {
    float e = __builtin_amdgcn_exp2f(x * -1.4426950408889634f);
    return __builtin_amdgcn_rcpf(1.0f + e);
}
static __device__ __forceinline__ float ftanh(float x) {
    float e = __builtin_amdgcn_exp2f(x * -2.8853900817779268f);
    return (1.0f - e) * __builtin_amdgcn_rcpf(1.0f + e);
}

// ---------------- prep: fp32 -> fp16 weights, combined decoder weights/biases ----------------
__global__ void k_prep(const float* __restrict__ eWih, const float* __restrict__ eWhh,
                       const float* __restrict__ ebih, const float* __restrict__ ebhh,
                       const float* __restrict__ dWih, const float* __restrict__ dWhh,
                       const float* __restrict__ dbih, const float* __restrict__ dbhh,
                       char* __restrict__ ws)
{
    f16* ewih = (f16*)(ws + WS_EWIH);
    f16* ewhh = (f16*)(ws + WS_EWHH);
    f16* dwc  = (f16*)(ws + WS_DWC);
    f16* dwhh = (f16*)(ws + WS_DWHH);
    float* bias = (float*)(ws + WS_BIAS);
    const int total = 12288 + 49152 + 65536 + 49152 + 1024;
    for (int i = blockIdx.x * 256 + threadIdx.x; i < total; i += gridDim.x * 256) {
        int j = i;
        if (j < 12288) {                       // enc Wih padded to K=32
            int g = j >> 5, k = j & 31;
            ewih[j] = (f16)((k < 29) ? eWih[g * 29 + k] : 0.0f);
            continue;
        }
        j -= 12288;
        if (j < 49152) { ewhh[j] = (f16)eWhh[j]; continue; }
        j -= 49152;
        if (j < 65536) {                       // dec combined [512][128]
            int row = j >> 7, k = j & 127;
            float v;
            if (row < 256)      v = dWih[row * 128 + k] + dWhh[row * 128 + k]; // rz combined (xin==h)
            else if (row < 384) v = dWih[row * 128 + k];                       // Wih_n
            else                v = dWhh[(row - 128) * 128 + k];               // Whh_n
            dwc[j] = (f16)v;
            continue;
        }
        j -= 65536;
        if (j < 49152) { dwhh[j] = (f16)dWhh[j]; continue; }
        j -= 49152;
        // biases
        if (j < 256)        bias[j] = ebih[j] + ebhh[j];
        else if (j < 384)   bias[j] = ebih[j];          // enc bxn
        else if (j < 512)   bias[j] = ebhh[j - 128];    // enc bhn
        else if (j < 768)   bias[j] = dbih[j - 512] + dbhh[j - 512];
        else if (j < 896)   bias[j] = dbih[j - 512];    // dec bxn
        else                bias[j] = dbhh[j - 640];    // dec bhn
    }
}

// ---------------- CNN path: fp32 exact, wave-per-image ----------------
__global__ __launch_bounds__(256) void k_cnn(
    const float* __restrict__ cin,  // (B,8,8,27) NHWC
    const float* __restrict__ w1, const float* __restrict__ b1,
    const float* __restrict__ w2, const float* __restrict__ b2,
    const float* __restrict__ fcw, const float* __restrict__ fcb,
    char* __restrict__ ws)
{
    __shared__ __align__(16) float in_s[4][1728];
    __shared__ float w1_s[3888];
    __shared__ float w2_s[2048];
    __shared__ float b1_s[16];
    __shared__ float b2_s[32];
    __shared__ float a1_s[4][144];
    __shared__ __align__(16) float v_s[4][128];
    float* z = (float*)(ws + WS_ZCNN);

    const int tid = threadIdx.x;
    const int base = blockIdx.x * 4;
    for (int i = tid; i < 4 * 1728; i += 256) ((float*)in_s)[i] = cin[(size_t)base * 1728 + i];
    for (int i = tid; i < 3888; i += 256) w1_s[i] = w1[i];
    for (int i = tid; i < 2048; i += 256) w2_s[i] = w2[i];
    if (tid < 16) b1_s[tid] = b1[tid];
    if (tid >= 32 && tid < 64) b2_s[tid - 32] = b2[tid - 32];
    __syncthreads();

    const int w = tid >> 6, lane = tid & 63;
    // conv1: 27ch 8x8 -> 16ch 3x3, k3 s2, relu
    #pragma unroll
    for (int rep = 0; rep < 3; rep++) {
        int o = lane + rep * 64;
        if (o < 144) {
            int co = o / 9, p = o % 9, oy = p / 3, ox = p % 3;
            float acc = b1_s[co];
            for (int ky = 0; ky < 3; ky++)
                for (int kx = 0; kx < 3; kx++) {
                    const float* ip = &in_s[w][((oy * 2 + ky) * 8 + (ox * 2 + kx)) * 27];
                    const float* wp = &w1_s[co * 243 + ky * 3 + kx];
                    #pragma unroll
                    for (int ci = 0; ci < 27; ci++) acc += ip[ci] * wp[ci * 9];
                }
            a1_s[w][o] = fmaxf(acc, 0.0f);
        }
    }
    __syncthreads();
    // conv2: 16ch 3x3 -> 32ch 2x2, k2 s1, relu; flat idx = co*4+y*2+x (CHW)
    #pragma unroll
    for (int rep = 0; rep < 2; rep++) {
        int o = lane + rep * 64;
        int co = o >> 2, p = o & 3, y = p >> 1, x = p & 1;
        float acc = b2_s[co];
        #pragma unroll
        for (int ci = 0; ci < 16; ci++)
            #pragma unroll
            for (int ky = 0; ky < 2; ky++)
                #pragma unroll
                for (int kx = 0; kx < 2; kx++)
                    acc += a1_s[w][ci * 9 + (y + ky) * 3 + (x + kx)] * w2_s[((co * 16 + ci) * 2 + ky) * 2 + kx];
        v_s[w][o] = fmaxf(acc, 0.0f);
    }
    __syncthreads();
    // fc 128->128, relu
    #pragma unroll
    for (int rep = 0; rep < 2; rep++) {
        int o = lane + rep * 64;
        float acc = fcb[o];
        const float4* wr = (const float4*)(fcw + o * 128);
        const float4* vv = (const float4*)(&v_s[w][0]);
        #pragma unroll
        for (int k = 0; k < 32; k++) {
            float4 a = wr[k], b = vv[k];
            acc += a.x * b.x + a.y * b.y + a.z * b.z + a.w * b.w;
        }
        z[(size_t)(base + w) * 128 + o] = fmaxf(acc, 0.0f);
    }
}

// ---------------- GRU enc+dec+heads: 16 rows/wg, wave owns 32 hidden cols ----------------
__global__ __launch_bounds__(256, 2) void k_gru(
    const float* __restrict__ lin,     // (8192,64,29)
    const char* __restrict__ ws,
    const float* __restrict__ dis_w, const float* __restrict__ dis_b,
    const float* __restrict__ value_w, const float* __restrict__ value_b,
    float* __restrict__ out)
{
    const int tid = threadIdx.x;
    const int wv = tid >> 6;
    const int lane = tid & 63;
    const int nl = lane & 15;
    const int quad = lane >> 4;
    const int j0 = wv * 32;
    const int row0 = blockIdx.x * 16;

    const f16* ewih = (const f16*)(ws + WS_EWIH);
    const f16* ewhh = (const f16*)(ws + WS_EWHH);
    const f16* dwc  = (const f16*)(ws + WS_DWC);
    const f16* dwhh = (const f16*)(ws + WS_DWHH);
    const float* bias = (const float*)(ws + WS_BIAS);
    const float* z_cnn = (const float*)(ws + WS_ZCNN);

    __shared__ __align__(16) f16 h_s[16][136];   // +8 pad: 2-way LDS conflicts only
    __shared__ __align__(16) f16 x_s[16][40];
    __shared__ __align__(16) float pn_s[16][260];

    for (int i = tid; i < 16 * 136; i += 256) ((f16*)h_s)[i] = (f16)0.0f;

    float ho[2][4];   // fp32 hidden state, C-layout slice (rows quad*4+r, col j0+16*tt+nl)
    #pragma unroll
    for (int tt = 0; tt < 2; tt++)
        #pragma unroll
        for (int r = 0; r < 4; r++) ho[tt][r] = 0.0f;

    // ================= encoder =================
    {
        float eb_r[2], eb_z[2], eb_xn[2], eb_hn[2];
        #pragma unroll
        for (int tt = 0; tt < 2; tt++) {
            int c = j0 + 16 * tt + nl;
            eb_r[tt]  = bias[c];
            eb_z[tt]  = bias[128 + c];
            eb_xn[tt] = bias[256 + c];
            eb_hn[tt] = bias[384 + c];
        }
        // register-resident B-frags of encoder weights
        f16x8 we_r[2][4], we_z[2][4], we_hn[2][4], we_xr[2], we_xz[2], we_xn[2];
        #pragma unroll
        for (int tt = 0; tt < 2; tt++) {
            int gr = j0 + 16 * tt + nl;
            int gz = 128 + gr;
            int gn = 256 + gr;
            #pragma unroll
            for (int kt = 0; kt < 4; kt++) {
                we_r[tt][kt]  = *(const f16x8*)(ewhh + gr * 128 + kt * 32 + quad * 8);
                we_z[tt][kt]  = *(const f16x8*)(ewhh + gz * 128 + kt * 32 + quad * 8);
                we_hn[tt][kt] = *(const f16x8*)(ewhh + gn * 128 + kt * 32 + quad * 8);
            }
            we_xr[tt] = *(const f16x8*)(ewih + gr * 32 + quad * 8);
            we_xz[tt] = *(const f16x8*)(ewih + gz * 32 + quad * 8);
            we_xn[tt] = *(const f16x8*)(ewih + gn * 32 + quad * 8);
        }

        for (int t = 0; t < 64; t++) {
            // stage x_t (16 rows x 29, pad to 32)
            #pragma unroll
            for (int it = 0; it < 2; it++) {
                int idx = tid + it * 256;
                int rr = idx >> 5, cc = idx & 31;
                float v = 0.0f;
                if (cc < 29) v = lin[(size_t)(row0 + rr) * 1856 + t * 29 + cc];
                x_s[rr][cc] = (f16)v;
            }
            __syncthreads();
            f16x8 ax = *(const f16x8*)(&x_s[nl][quad * 8]);
            f16x8 ah[4];
            #pragma unroll
            for (int kt = 0; kt < 4; kt++) ah[kt] = *(const f16x8*)(&h_s[nl][kt * 32 + quad * 8]);
            __syncthreads();   // all frag reads done before any h_s write below

            #pragma unroll
            for (int tt = 0; tt < 2; tt++) {
                f32x4 aR  = {eb_r[tt], eb_r[tt], eb_r[tt], eb_r[tt]};
                f32x4 aZ  = {eb_z[tt], eb_z[tt], eb_z[tt], eb_z[tt]};
                f32x4 aXN = {eb_xn[tt], eb_xn[tt], eb_xn[tt], eb_xn[tt]};
                f32x4 aHN = {eb_hn[tt], eb_hn[tt], eb_hn[tt], eb_hn[tt]};
                aR  = mfma16(ax, we_xr[tt], aR);
                aZ  = mfma16(ax, we_xz[tt], aZ);
                aXN = mfma16(ax, we_xn[tt], aXN);
                #pragma unroll
                for (int kt = 0; kt < 4; kt++) {
                    aR  = mfma16(ah[kt], we_r[tt][kt], aR);
                    aZ  = mfma16(ah[kt], we_z[tt][kt], aZ);
                    aHN = mfma16(ah[kt], we_hn[tt][kt], aHN);
                }
                #pragma unroll
                for (int r = 0; r < 4; r++) {
                    float rg = fsig(aR[r]);
                    float zg = fsig(aZ[r]);
                    float ng = ftanh(aXN[r] + rg * aHN[r]);
                    float h = (1.0f - zg) * ng + zg * ho[tt][r];
                    ho[tt][r] = h;
                    h_s[quad * 4 + r][j0 + 16 * tt + nl] = (f16)h;
                }
            }
        }
    }

    // ================= decoder =================
    float db_r[2], db_z[2], db_xn[2], db_hn[2];
    #pragma unroll
    for (int tt = 0; tt < 2; tt++) {
        int c = j0 + 16 * tt + nl;
        db_r[tt]  = bias[512 + c];
        db_z[tt]  = bias[640 + c];
        db_xn[tt] = bias[768 + c];
        db_hn[tt] = bias[896 + c];
    }
    // step 0: xin = 0 -> gx = bih; stream Whh frags once
    {
        __syncthreads();
        f16x8 ah[4];
        #pragma unroll
        for (int kt = 0; kt < 4; kt++) ah[kt] = *(const f16x8*)(&h_s[nl][kt * 32 + quad * 8]);
        __syncthreads();
        #pragma unroll
        for (int tt = 0; tt < 2; tt++) {
            int gr = j0 + 16 * tt + nl;
            f32x4 aR  = {db_r[tt], db_r[tt], db_r[tt], db_r[tt]};
            f32x4 aZ  = {db_z[tt], db_z[tt], db_z[tt], db_z[tt]};
            f32x4 aHN = {db_hn[tt], db_hn[tt], db_hn[tt], db_hn[tt]};
            #pragma unroll
            for (int kt = 0; kt < 4; kt++) {
                aR  = mfma16(ah[kt], *(const f16x8*)(dwhh + gr * 128 + kt * 32 + quad * 8), aR);
                aZ  = mfma16(ah[kt], *(const f16x8*)(dwhh + (128 + gr) * 128 + kt * 32 + quad * 8), aZ);
                aHN = mfma16(ah[kt], *(const f16x8*)(dwhh + (256 + gr) * 128 + kt * 32 + quad * 8), aHN);
            }
            #pragma unroll
            for (int r = 0; r < 4; r++) {
                float rg = fsig(aR[r]);
                float zg = fsig(aZ[r]);
                float ng = ftanh(db_xn[tt] + rg * aHN[r]);
                float h = (1.0f - zg) * ng + zg * ho[tt][r];
                ho[tt][r] = h;
                h_s[quad * 4 + r][j0 + 16 * tt + nl] = (f16)h;
            }
        }
    }
    // steps 1..63: xin == h -> combined weights, register-resident
    {
        f16x8 wd_r[2][4], wd_z[2][4], wd_xn[2][4], wd_hn[2][4];
        #pragma unroll
        for (int tt = 0; tt < 2; tt++) {
            int gr = j0 + 16 * tt + nl;
            #pragma unroll
            for (int kt = 0; kt < 4; kt++) {
                wd_r[tt][kt]  = *(const f16x8*)(dwc + gr * 128 + kt * 32 + quad * 8);
                wd_z[tt][kt]  = *(const f16x8*)(dwc + (128 + gr) * 128 + kt * 32 + quad * 8);
                wd_xn[tt][kt] = *(const f16x8*)(dwc + (256 + gr) * 128 + kt * 32 + quad * 8);
                wd_hn[tt][kt] = *(const f16x8*)(dwc + (384 + gr) * 128 + kt * 32 + quad * 8);
            }
        }
        for (int t = 1; t < 64; t++) {
            __syncthreads();   // prior step writes visible
            f16x8 ah[4];
            #pragma unroll
            for (int kt = 0; kt < 4; kt++) ah[kt] = *(const f16x8*)(&h_s[nl][kt * 32 + quad * 8]);
            __syncthreads();   // reads done before writes
            #pragma unroll
            for (int tt = 0; tt < 2; tt++) {
                f32x4 aR  = {db_r[tt], db_r[tt], db_r[tt], db_r[tt]};
                f32x4 aZ  = {db_z[tt], db_z[tt], db_z[tt], db_z[tt]};
                f32x4 aXN = {db_xn[tt], db_xn[tt], db_xn[tt], db_xn[tt]};
                f32x4 aHN = {db_hn[tt], db_hn[tt], db_hn[tt], db_hn[tt]};
                #pragma unroll
                for (int kt = 0; kt < 4; kt++) {
                    aR  = mfma16(ah[kt], wd_r[tt][kt], aR);
                    aZ  = mfma16(ah[kt], wd_z[tt][kt], aZ);
                    aXN = mfma16(ah[kt], wd_xn[tt][kt], aXN);
                    aHN = mfma16(ah[kt], wd_hn[tt][kt], aHN);
                }
                #pragma unroll
                for (int r = 0; r < 4; r++) {
                    float rg = fsig(aR[r]);
                    float zg = fsig(aZ[r]);
                    float ng = ftanh(aXN[r] + rg * aHN[r]);
                    float h = (1.0f - zg) * ng + zg * ho[tt][r];
                    ho[tt][r] = h;
                    h_s[quad * 4 + r][j0 + 16 * tt + nl] = (f16)h;
                }
            }
        }
    }

    // ================= heads =================
    #pragma unroll
    for (int tt = 0; tt < 2; tt++)
        #pragma unroll
        for (int r = 0; r < 4; r++)
            pn_s[quad * 4 + r][128 + j0 + 16 * tt + nl] = ho[tt][r];   // fp32 z_pn
    for (int i = tid; i < 16 * 128; i += 256) {
        int rr = i >> 7, cc = i & 127;
        pn_s[rr][cc] = z_cnn[(size_t)(row0 + rr) * 128 + cc];
    }
    __syncthreads();

    const int rr = tid & 15, og = tid >> 4;
    const float4* pr4 = (const float4*)(&pn_s[rr][0]);
    for (int o = og; o < 79; o += 16) {
        const float* wrow = (o < 78) ? (dis_w + o * 256) : value_w;
        float acc = (o < 78) ? dis_b[o] : value_b[0];
        const float4* wr4 = (const float4*)wrow;
        #pragma unroll 8
        for (int k = 0; k < 64; k++) {
            float4 a = wr4[k], b = pr4[k];
            acc += a.x * b.x + a.y * b.y + a.z * b.z + a.w * b.w;
        }
        if (o < 78) out[(size_t)(row0 + rr) * 78 + o] = acc;
        else        out[(size_t)8192 * 78 + row0 + rr] = acc;
    }
}

extern "C" void kernel_launch(void* const* d_in, const int* in_sizes, int n_in,
                              void* d_out, int out_size, void* d_ws, size_t ws_size,
                              hipStream_t stream)
{
    (void)in_sizes; (void)n_in; (void)out_size; (void)ws_size;
    const float* cnn  = (const float*)d_in[0];
    const float* lin  = (const float*)d_in[1];
    const float* c1w  = (const float*)d_in[2];
    const float* c1b  = (const float*)d_in[3];
    const float* c2w  = (const float*)d_in[4];
    const float* c2b  = (const float*)d_in[5];
    const float* fcw  = (const float*)d_in[6];
    const float* fcb  = (const float*)d_in[7];
    const float* eWih = (const float*)d_in[8];
    const float* eWhh = (const float*)d_in[9];
    const float* ebih = (const float*)d_in[10];
    const float* ebhh = (const float*)d_in[11];
    const float* dWih = (const float*)d_in[12];
    const float* dWhh = (const float*)d_in[13];
    const float* dbih = (const float*)d_in[14];
    const float* dbhh = (const float*)d_in[15];
    const float* disw = (const float*)d_in[16];
    const float* disb = (const float*)d_in[17];
    const float* vw   = (const float*)d_in[18];
    const float* vb   = (const float*)d_in[19];
    char* ws = (char*)d_ws;
    float* out = (float*)d_out;

    hipLaunchKernelGGL(k_prep, dim3(128), dim3(256), 0, stream,
                       eWih, eWhh, ebih, ebhh, dWih, dWhh, dbih, dbhh, ws);
    hipLaunchKernelGGL(k_cnn, dim3(2048), dim3(256), 0, stream,
                       cnn, c1w, c1b, c2w, c2b, fcw, fcb, ws);
    hipLaunchKernelGGL(k_gru, dim3(512), dim3(256), 0, stream,
                       lin, ws, disw, disb, vw, vb, out);
}

// Round 3
// 380.948 us; speedup vs baseline: 1.2388x; 1.2388x over previous
//
#include <hip/hip_runtime.h>

typedef _Float16 f16;
typedef _Float16 f16x8 __attribute__((ext_vector_type(8)));
typedef float f32x4 __attribute__((ext_vector_type(4)));

// ---- workspace layout (bytes) ----
#define WS_ZCNN 0                      // 8192*128 f32 = 4 MiB
#define WS_EWIH 4194304                // enc Wih f16 [384][32] (k>=29 zero)
#define WS_EWHH 4218880                // enc Whh f16 [384][128]
#define WS_DWC  4317184                // dec combined f16 [512][128]
#define WS_DWHH 4448256                // dec Whh f16 [384][128]
#define WS_BIAS 4546560                // f32[1024]
#define WS_W1F  4550656                // conv1 B-frags f16 [9][16][32]
#define WS_W2F  4559872                // conv2 B-frags f16 [2][32][32]
#define WS_FCWF 4563968                // fc weights f16 [128][128]

static __device__ __forceinline__ f32x4 mfma16(f16x8 a, f16x8 b, f32x4 c) {
    return __builtin_amdgcn_mfma_f32_16x16x32_f16(a, b, c, 0, 0, 0);
}
static __device__ __forceinline__ float fexp2n(float x) {   // 2^(-x*log2e)
    return __builtin_amdgcn_exp2f(x * -1.4426950408889634f);
}

// ---------------- prep: f32 -> f16 packs ----------------
__global__ void k_prep(const float* __restrict__ eWih, const float* __restrict__ eWhh,
                       const float* __restrict__ ebih, const float* __restrict__ ebhh,
                       const float* __restrict__ dWih, const float* __restrict__ dWhh,
                       const float* __restrict__ dbih, const float* __restrict__ dbhh,
                       const float* __restrict__ w1, const float* __restrict__ w2,
                       const float* __restrict__ fcw,
                       char* __restrict__ ws)
{
    f16* ewih = (f16*)(ws + WS_EWIH);
    f16* ewhh = (f16*)(ws + WS_EWHH);
    f16* dwc  = (f16*)(ws + WS_DWC);
    f16* dwhh = (f16*)(ws + WS_DWHH);
    float* bias = (float*)(ws + WS_BIAS);
    f16* w1f = (f16*)(ws + WS_W1F);
    f16* w2f = (f16*)(ws + WS_W2F);
    f16* fcwf = (f16*)(ws + WS_FCWF);
    const int total = 12288 + 49152 + 65536 + 49152 + 1024 + 4608 + 2048 + 16384;
    for (int i = blockIdx.x * 256 + threadIdx.x; i < total; i += gridDim.x * 256) {
        int j = i;
        if (j < 12288) { int g = j >> 5, k = j & 31;
            ewih[j] = (f16)((k < 29) ? eWih[g * 29 + k] : 0.0f); continue; }
        j -= 12288;
        if (j < 49152) { ewhh[j] = (f16)eWhh[j]; continue; }
        j -= 49152;
        if (j < 65536) { int row = j >> 7, k = j & 127; float v;
            if (row < 256)      v = dWih[row * 128 + k] + dWhh[row * 128 + k];
            else if (row < 384) v = dWih[row * 128 + k];
            else                v = dWhh[(row - 128) * 128 + k];
            dwc[j] = (f16)v; continue; }
        j -= 65536;
        if (j < 49152) { dwhh[j] = (f16)dWhh[j]; continue; }
        j -= 49152;
        if (j < 1024) {
            if (j < 256)        bias[j] = ebih[j] + ebhh[j];
            else if (j < 384)   bias[j] = ebih[j];
            else if (j < 512)   bias[j] = ebhh[j - 128];
            else if (j < 768)   bias[j] = dbih[j - 512] + dbhh[j - 512];
            else if (j < 896)   bias[j] = dbih[j - 512];
            else                bias[j] = dbhh[j - 640];
            continue; }
        j -= 1024;
        if (j < 4608) {   // w1f[kk][co][k]: w1 (16,27,3,3) OIHW
            int kk = j >> 9, rem = j & 511, co = rem >> 5, k = rem & 31;
            w1f[j] = (f16)((k < 27) ? w1[co * 243 + k * 9 + kk] : 0.0f); continue; }
        j -= 4608;
        if (j < 2048) {   // w2f[s][co][k]: k<16 -> kk2=2s,ci=k ; k>=16 -> kk2=2s+1,ci=k-16
            int s = j >> 10, rem = j & 1023, co = rem >> 5, k = rem & 31;
            int kk2 = 2 * s + (k >= 16), ci = k & 15;
            w2f[j] = (f16)w2[co * 64 + ci * 4 + kk2]; continue; }
        j -= 2048;
        fcwf[j] = (f16)fcw[j];
    }
}

// ---------------- CNN: 16 images/block, MFMA f16 ----------------
__global__ __launch_bounds__(256) void k_cnn(
    const float* __restrict__ cin,
    const float* __restrict__ b1, const float* __restrict__ b2,
    const float* __restrict__ fcb,
    char* __restrict__ ws)
{
    __shared__ __align__(16) f16 in_t[16][64][32];   // 64 KB
    __shared__ __align__(16) f16 a1f[16][9][24];     // conv1 out (relu)
    __shared__ __align__(16) f16 vf[16][136];        // flat CHW conv2 out

    const int tid = threadIdx.x;
    const int base = blockIdx.x * 16;
    const f16* w1f = (const f16*)(ws + WS_W1F);
    const f16* w2f = (const f16*)(ws + WS_W2F);
    const f16* fcwf = (const f16*)(ws + WS_FCWF);
    float* z = (float*)(ws + WS_ZCNN);

    for (int i = tid; i < 16 * 1728; i += 256) {
        int img = i / 1728, rem = i % 1728;
        int pix = rem / 27, ci = rem % 27;
        in_t[img][pix][ci] = (f16)cin[(size_t)base * 1728 + i];
    }
    for (int i = tid; i < 16 * 64 * 5; i += 256) {
        int img = i / 320, r2 = i % 320;
        in_t[img][r2 / 5][27 + r2 % 5] = (f16)0.0f;
    }
    __syncthreads();

    const int wv = tid >> 6, lane = tid & 63, nl = lane & 15, quad = lane >> 4;

    // conv1: 9 MFMAs per output position; A rows = contiguous channel vectors
    f16x8 bw1[9];
    #pragma unroll
    for (int kk = 0; kk < 9; kk++)
        bw1[kk] = *(const f16x8*)(w1f + (kk * 16 + nl) * 32 + quad * 8);
    float b1v = b1[nl];
    for (int p = wv; p < 9; p += 4) {
        int oy = p / 3, ox = p % 3;
        f32x4 acc = {b1v, b1v, b1v, b1v};
        #pragma unroll
        for (int kk = 0; kk < 9; kk++) {
            int pix = (2 * oy + kk / 3) * 8 + (2 * ox + kk % 3);
            f16x8 a = *(const f16x8*)(&in_t[nl][pix][quad * 8]);
            acc = mfma16(a, bw1[kk], acc);
        }
        #pragma unroll
        for (int r = 0; r < 4; r++)
            a1f[quad * 4 + r][p][nl] = (f16)fmaxf(acc[r], 0.0f);
    }
    __syncthreads();

    // conv2: wave = output pos (y,x); K=64 as 2 MFMA k-steps
    {
        int y = wv >> 1, x = wv & 1;
        #pragma unroll
        for (int nt = 0; nt < 2; nt++) {
            float bv = b2[nt * 16 + nl];
            f32x4 acc = {bv, bv, bv, bv};
            #pragma unroll
            for (int s = 0; s < 2; s++) {
                int kk2 = 2 * s + (quad >> 1);
                int pos1 = (y + (kk2 >> 1)) * 3 + (x + (kk2 & 1));
                f16x8 a = *(const f16x8*)(&a1f[nl][pos1][(quad & 1) * 8]);
                f16x8 b = *(const f16x8*)(w2f + ((size_t)s * 32 + nt * 16 + nl) * 32 + quad * 8);
                acc = mfma16(a, b, acc);
            }
            #pragma unroll
            for (int r = 0; r < 4; r++)
                vf[quad * 4 + r][(nt * 16 + nl) * 4 + (y * 2 + x)] = (f16)fmaxf(acc[r], 0.0f);
        }
    }
    __syncthreads();

    // fc 128->128: wave wv -> outputs wv*32..wv*32+31
    #pragma unroll
    for (int nt = 0; nt < 2; nt++) {
        int o = wv * 32 + nt * 16 + nl;
        float bv = fcb[o];
        f32x4 acc = {bv, bv, bv, bv};
        #pragma unroll
        for (int kt = 0; kt < 4; kt++) {
            f16x8 a = *(const f16x8*)(&vf[nl][kt * 32 + quad * 8]);
            f16x8 b = *(const f16x8*)(fcwf + o * 128 + kt * 32 + quad * 8);
            acc = mfma16(a, b, acc);
        }
        #pragma unroll
        for (int r = 0; r < 4; r++)
            z[(size_t)(base + quad * 4 + r) * 128 + o] = fmaxf(acc[r], 0.0f);
    }
}

// ---------------- GRU: 512 threads, 16 rows/block, wave owns 16 cols ----------------
__global__ __launch_bounds__(512, 4) void k_gru(
    const float* __restrict__ lin,
    const char* __restrict__ ws,
    const float* __restrict__ dis_w, const float* __restrict__ dis_b,
    const float* __restrict__ value_w, const float* __restrict__ value_b,
    float* __restrict__ out)
{
    const int tid = threadIdx.x;
    const int wv = tid >> 6;
    const int lane = tid & 63;
    const int nl = lane & 15;
    const int quad = lane >> 4;
    const int j0 = wv * 16;
    const int row0 = blockIdx.x * 16;

    const f16* ewih = (const f16*)(ws + WS_EWIH);
    const f16* ewhh = (const f16*)(ws + WS_EWHH);
    const f16* dwc  = (const f16*)(ws + WS_DWC);
    const f16* dwhh = (const f16*)(ws + WS_DWHH);
    const float* bias = (const float*)(ws + WS_BIAS);
    const float* z_cnn = (const float*)(ws + WS_ZCNN);

    // h_s: swizzled (rows 8-15 rotated +16 cols) -> conflict-free b16 writes, clean b128 reads
    __shared__ __align__(16) f16 h_s[2][16][136];
    __shared__ __align__(16) f16 x_s[2][16][32];
    __shared__ __align__(16) float pn_s[16][264];

    for (int i = tid; i < 2 * 16 * 136; i += 512) ((f16*)h_s)[i] = (f16)0.0f;

    const int rsw = (nl & 8) ? 16 : 0;    // read-side swizzle (row = nl)
    const int wrow = quad * 4;            // write rows wrow..wrow+3
    const int wsw = (quad >= 2) ? 16 : 0; // write-side swizzle (rows 8-15)
    const int wcol = (j0 + nl + wsw) & 127;

    float ho[4];
    #pragma unroll
    for (int r = 0; r < 4; r++) ho[r] = 0.0f;

    const int xr = tid >> 5, xc = tid & 31;   // x staging: 16 rows x 32 cols

    // ================= encoder =================
    {
        float eb_r, eb_z, eb_xn, eb_hn;
        { int c = j0 + nl;
          eb_r = bias[c]; eb_z = bias[128 + c]; eb_xn = bias[256 + c]; eb_hn = bias[384 + c]; }
        f16x8 we_r[4], we_z[4], we_hn[4], we_xr, we_xz, we_xn;
        { int gr = j0 + nl;
          #pragma unroll
          for (int kt = 0; kt < 4; kt++) {
              we_r[kt]  = *(const f16x8*)(ewhh + gr * 128 + kt * 32 + quad * 8);
              we_z[kt]  = *(const f16x8*)(ewhh + (128 + gr) * 128 + kt * 32 + quad * 8);
              we_hn[kt] = *(const f16x8*)(ewhh + (256 + gr) * 128 + kt * 32 + quad * 8);
          }
          we_xr = *(const f16x8*)(ewih + gr * 32 + quad * 8);
          we_xz = *(const f16x8*)(ewih + (128 + gr) * 32 + quad * 8);
          we_xn = *(const f16x8*)(ewih + (256 + gr) * 32 + quad * 8);
        }

        float xv = (xc < 29) ? lin[(size_t)(row0 + xr) * 1856 + xc] : 0.0f;

        for (int t = 0; t < 64; t++) {
            x_s[t & 1][xr][xc] = (f16)xv;
            __syncthreads();   // x_s[t] + h writes of t-1 visible; WAR safe (double buffers)
            f16x8 ax = *(const f16x8*)(&x_s[t & 1][nl][quad * 8]);
            f16x8 ah[4];
            #pragma unroll
            for (int kt = 0; kt < 4; kt++)
                ah[kt] = *(const f16x8*)(&h_s[t & 1][nl][((kt * 32 + quad * 8 + rsw) & 127)]);
            if (t < 63) xv = (xc < 29) ? lin[(size_t)(row0 + xr) * 1856 + (t + 1) * 29 + xc] : 0.0f;

            f32x4 aR  = {eb_r, eb_r, eb_r, eb_r};
            f32x4 aZ  = {eb_z, eb_z, eb_z, eb_z};
            f32x4 aXN = {eb_xn, eb_xn, eb_xn, eb_xn};
            f32x4 aHN = {eb_hn, eb_hn, eb_hn, eb_hn};
            aR  = mfma16(ax, we_xr, aR);
            aZ  = mfma16(ax, we_xz, aZ);
            aXN = mfma16(ax, we_xn, aXN);
            #pragma unroll
            for (int kt = 0; kt < 4; kt++) {
                aR  = mfma16(ah[kt], we_r[kt], aR);
                aZ  = mfma16(ah[kt], we_z[kt], aZ);
                aHN = mfma16(ah[kt], we_hn[kt], aHN);
            }
            #pragma unroll
            for (int r = 0; r < 4; r++) {
                float ea = fexp2n(aR[r]), eb = fexp2n(aZ[r]);
                float s1 = 1.0f + ea, s2 = 1.0f + eb;
                float R = __builtin_amdgcn_rcpf(s1 * s2);
                float rg = s2 * R, zg = s1 * R;
                float ec = fexp2n(2.0f * (aXN[r] + rg * aHN[r]));
                float ng = (1.0f - ec) * __builtin_amdgcn_rcpf(1.0f + ec);
                float h = (1.0f - zg) * ng + zg * ho[r];
                ho[r] = h;
                h_s[(t + 1) & 1][wrow + r][wcol] = (f16)h;
            }
        }
    }

    // ================= decoder =================
    float db_r, db_z, db_xn, db_hn;
    { int c = j0 + nl;
      db_r = bias[512 + c]; db_z = bias[640 + c]; db_xn = bias[768 + c]; db_hn = bias[896 + c]; }

    // step 0: xin = 0 -> gx = bih; Whh-only frags streamed once
    {
        __syncthreads();
        f16x8 ah[4];
        #pragma unroll
        for (int kt = 0; kt < 4; kt++)
            ah[kt] = *(const f16x8*)(&h_s[0][nl][((kt * 32 + quad * 8 + rsw) & 127)]);
        int gr = j0 + nl;
        f32x4 aR  = {db_r, db_r, db_r, db_r};
        f32x4 aZ  = {db_z, db_z, db_z, db_z};
        f32x4 aHN = {db_hn, db_hn, db_hn, db_hn};
        #pragma unroll
        for (int kt = 0; kt < 4; kt++) {
            aR  = mfma16(ah[kt], *(const f16x8*)(dwhh + gr * 128 + kt * 32 + quad * 8), aR);
            aZ  = mfma16(ah[kt], *(const f16x8*)(dwhh + (128 + gr) * 128 + kt * 32 + quad * 8), aZ);
            aHN = mfma16(ah[kt], *(const f16x8*)(dwhh + (256 + gr) * 128 + kt * 32 + quad * 8), aHN);
        }
        #pragma unroll
        for (int r = 0; r < 4; r++) {
            float ea = fexp2n(aR[r]), eb = fexp2n(aZ[r]);
            float s1 = 1.0f + ea, s2 = 1.0f + eb;
            float R = __builtin_amdgcn_rcpf(s1 * s2);
            float rg = s2 * R, zg = s1 * R;
            float ec = fexp2n(2.0f * (db_xn + rg * aHN[r]));
            float ng = (1.0f - ec) * __builtin_amdgcn_rcpf(1.0f + ec);
            float h = (1.0f - zg) * ng + zg * ho[r];
            ho[r] = h;
            h_s[1][wrow + r][wcol] = (f16)h;
        }
    }
    // steps 1..63: xin == h -> combined weights, register-resident
    {
        f16x8 wd_r[4], wd_z[4], wd_xn[4], wd_hn[4];
        { int gr = j0 + nl;
          #pragma unroll
          for (int kt = 0; kt < 4; kt++) {
              wd_r[kt]  = *(const f16x8*)(dwc + gr * 128 + kt * 32 + quad * 8);
              wd_z[kt]  = *(const f16x8*)(dwc + (128 + gr) * 128 + kt * 32 + quad * 8);
              wd_xn[kt] = *(const f16x8*)(dwc + (256 + gr) * 128 + kt * 32 + quad * 8);
              wd_hn[kt] = *(const f16x8*)(dwc + (384 + gr) * 128 + kt * 32 + quad * 8);
          }
        }
        for (int t = 1; t < 64; t++) {
            __syncthreads();
            f16x8 ah[4];
            #pragma unroll
            for (int kt = 0; kt < 4; kt++)
                ah[kt] = *(const f16x8*)(&h_s[t & 1][nl][((kt * 32 + quad * 8 + rsw) & 127)]);
            f32x4 aR  = {db_r, db_r, db_r, db_r};
            f32x4 aZ  = {db_z, db_z, db_z, db_z};
            f32x4 aXN = {db_xn, db_xn, db_xn, db_xn};
            f32x4 aHN = {db_hn, db_hn, db_hn, db_hn};
            #pragma unroll
            for (int kt = 0; kt < 4; kt++) {
                aR  = mfma16(ah[kt], wd_r[kt], aR);
                aZ  = mfma16(ah[kt], wd_z[kt], aZ);
                aXN = mfma16(ah[kt], wd_xn[kt], aXN);
                aHN = mfma16(ah[kt], wd_hn[kt], aHN);
            }
            #pragma unroll
            for (int r = 0; r < 4; r++) {
                float ea = fexp2n(aR[r]), eb = fexp2n(aZ[r]);
                float s1 = 1.0f + ea, s2 = 1.0f + eb;
                float R = __builtin_amdgcn_rcpf(s1 * s2);
                float rg = s2 * R, zg = s1 * R;
                float ec = fexp2n(2.0f * (aXN[r] + rg * aHN[r]));
                float ng = (1.0f - ec) * __builtin_amdgcn_rcpf(1.0f + ec);
                float h = (1.0f - zg) * ng + zg * ho[r];
                ho[r] = h;
                h_s[(t + 1) & 1][wrow + r][wcol] = (f16)h;
            }
        }
    }

    // ================= heads =================
    #pragma unroll
    for (int r = 0; r < 4; r++)
        pn_s[wrow + r][128 + j0 + nl] = ho[r];
    for (int i = tid; i < 16 * 128; i += 512) {
        int rr = i >> 7, cc = i & 127;
        pn_s[rr][cc] = z_cnn[(size_t)(row0 + rr) * 128 + cc];
    }
    __syncthreads();

    const int rr = tid & 15, og = tid >> 4;   // og 0..31
    const float4* pr4 = (const float4*)(&pn_s[rr][0]);
    for (int o = og; o < 79; o += 32) {
        const float* wrow_p = (o < 78) ? (dis_w + o * 256) : value_w;
        float acc = (o < 78) ? dis_b[o] : value_b[0];
        const float4* wr4 = (const float4*)wrow_p;
        #pragma unroll 8
        for (int k = 0; k < 64; k++) {
            float4 a = wr4[k], b = pr4[k];
            acc += a.x * b.x + a.y * b.y + a.z * b.z + a.w * b.w;
        }
        if (o < 78) out[(size_t)(row0 + rr) * 78 + o] = acc;
        else        out[(size_t)8192 * 78 + row0 + rr] = acc;
    }
}

extern "C" void kernel_launch(void* const* d_in, const int* in_sizes, int n_in,
                              void* d_out, int out_size, void* d_ws, size_t ws_size,
                              hipStream_t stream)
{
    (void)in_sizes; (void)n_in; (void)out_size; (void)ws_size;
    const float* cnn  = (const float*)d_in[0];
    const float* lin  = (const float*)d_in[1];
    const float* c1w  = (const float*)d_in[2];
    const float* c1b  = (const float*)d_in[3];
    const float* c2w  = (const float*)d_in[4];
    const float* c2b  = (const float*)d_in[5];
    const float* fcw  = (const float*)d_in[6];
    const float* fcb  = (const float*)d_in[7];
    const float* eWih = (const float*)d_in[8];
    const float* eWhh = (const float*)d_in[9];
    const float* ebih = (const float*)d_in[10];
    const float* ebhh = (const float*)d_in[11];
    const float* dWih = (const float*)d_in[12];
    const float* dWhh = (const float*)d_in[13];
    const float* dbih = (const float*)d_in[14];
    const float* dbhh = (const float*)d_in[15];
    const float* disw = (const float*)d_in[16];
    const float* disb = (const float*)d_in[17];
    const float* vw   = (const float*)d_in[18];
    const float* vb   = (const float*)d_in[19];
    char* ws = (char*)d_ws;
    float* out = (float*)d_out;

    hipLaunchKernelGGL(k_prep, dim3(128), dim3(256), 0, stream,
                       eWih, eWhh, ebih, ebhh, dWih, dWhh, dbih, dbhh,
                       c1w, c2w, fcw, ws);
    hipLaunchKernelGGL(k_cnn, dim3(512), dim3(256), 0, stream,
                       cnn, c1b, c2b, fcb, ws);
    hipLaunchKernelGGL(k_gru, dim3(512), dim3(512), 0, stream,
                       lin, ws, disw, disb, vw, vb, out);
}